// Round 12
// baseline (963.616 us; speedup 1.0000x reference)
//
#include <hip/hip_runtime.h>
#include <hip/hip_bf16.h>

#define B_ 64
#define S_ 4096
#define H_ 512
#define E_ 512
#define NEG_INF_ -1e10f

typedef __attribute__((ext_vector_type(8))) short short8;
typedef __attribute__((ext_vector_type(16))) float f32x16;

static __device__ __forceinline__ unsigned short f2bf(float f) {
    union { float f; unsigned u; } v; v.f = f;
    unsigned x = v.u;
    x += 0x7FFFu + ((x >> 16) & 1u);   // round-to-nearest-even
    return (unsigned short)(x >> 16);
}

// vendor RNE pair conversion (verified r3/r5-r11: absmax 4.9e-4)
static __device__ __forceinline__ unsigned pk2(float lo, float hi) {
    float2 f; f.x = lo; f.y = hi;
    union { __hip_bfloat162 h; unsigned u; } c;
    c.h = __float22bfloat162_rn(f);
    return c.u;
}

static __device__ __forceinline__ void gload_lds16(const void* g, void* l) {
    __builtin_amdgcn_global_load_lds(
        (const __attribute__((address_space(1))) void*)g,
        (__attribute__((address_space(3))) void*)l, 16, 0, 0);
}

#define VMCNT6  do { asm volatile("s_waitcnt vmcnt(6)"  ::: "memory"); __builtin_amdgcn_sched_barrier(0); } while (0)
#define VMCNT0  do { asm volatile("s_waitcnt vmcnt(0)"  ::: "memory"); __builtin_amdgcn_sched_barrier(0); } while (0)

// ---------------- prep: Wkt[h][e] = bf16(Wk[e][h]) ----------------
__global__ void prep_wkt(const float* __restrict__ wk, unsigned short* __restrict__ wkt) {
    int idx = blockIdx.x * 256 + threadIdx.x;
    int h = idx >> 9, e = idx & 511;
    wkt[idx] = f2bf(wk[e * H_ + h]);
}

// ---------------- prep: qb[b][h] = hidden[b]@Wq[:,h] + bq[h] + bk[h] ----------------
__global__ void prep_qb(const float* __restrict__ hidden, const float* __restrict__ wq,
                        const float* __restrict__ bq, const float* __restrict__ bk,
                        float* __restrict__ qb) {
    __shared__ float hid[H_];
    int b = blockIdx.x, t = threadIdx.x;           // 256 threads
    hid[t]       = hidden[b * H_ + t];
    hid[t + 256] = hidden[b * H_ + t + 256];
    __syncthreads();
    for (int hh = t; hh < H_; hh += 256) {
        float s = 0.f;
        for (int e = 0; e < H_; ++e) s += hid[e] * wq[e * H_ + hh];
        qb[b * H_ + hh] = s + bq[hh] + bk[hh];
    }
}

// ---------------- main: partial scores over one 128-col n-chunk ----------------
// r10 structure FIXED: the r10 failure was VGPR spill from launch_bounds(256,3) (cap 84 <
// needed ~124 -> 168 MB scratch). Now launch_bounds(256,4) (cap 128) + depth-2 A (2 reg sets
// = 32 VGPR) + B ring-3 (24 KB LDS) -> 4 blocks/CU (16 independent waves/CU, VGPR-bound).
// grid 8192: xcd-chunked -> (b, s-tile 128, n-tile 128). block 256 thr = 4 waves,
// wave w owns M-strip rows w*32..w*32+31 x ALL 128 N-cols (acc[4]).
// A (enc f32): direct-to-fragment loads -> pk2 -> af (no A LDS, no writeA, no lgkm hop).
// B (Wkt bf16): global_load_lds DMA, ring-3, XOR layout, source-permuted [r5+: 0-conflict].
// Runtime kc loop, depth-2, counted vmcnt(6/0), one s_barrier per kc (B publish only).
__global__ __launch_bounds__(256, 4) void scores_kernel(
    const float* __restrict__ enc, const unsigned short* __restrict__ wkt,
    const float* __restrict__ qb, const float* __restrict__ wv,
    float* __restrict__ part)
{
    __shared__ char lds[24576];   // B0..B2 @ 8KB; epilogue reuses [0, 19456)

    int id = blockIdx.x;
    int xcd = id & 7, qq = id >> 3;
    int logical = xcd * 1024 + qq;
    int b  = logical >> 7;
    int r  = logical & 127;
    int st = r >> 2, nt = r & 3;
    int s0 = st * 128;

    const int tid  = threadIdx.x;
    const int lane = tid & 63;
    const int wave = tid >> 6;       // M-strip 0..3
    const int l31  = lane & 31;
    const int g    = lane >> 5;

    // A: lane-private fragment row pointer (row = s0 + wave*32 + l31, k base g*8)
    const float* aRow = enc + ((size_t)b * S_ + s0 + wave * 32 + l31) * E_ + g * 8;

    auto loadA = [&](int kc, float4 (&rg)[4]) {
        const float* p = aRow + kc * 32;
        rg[0] = *(const float4*)(p);          // ks=0, k = kc*32+g*8 .. +3
        rg[1] = *(const float4*)(p + 4);      //        .. +7
        rg[2] = *(const float4*)(p + 16);     // ks=1
        rg[3] = *(const float4*)(p + 20);
    };
    // ---- B: 128 n x 32 k bf16 = 8KB DMA; stored [sn 32][16]: sl = ss^(sn&15); n=(sl>>2)*32+sn; k=(sl&3)*8
    auto stageB = [&](int kc, char* buf) {
#pragma unroll
        for (int p = 0; p < 2; ++p) {
            int gi0 = p * 256 + wave * 64;
            char* db = buf + gi0 * 16;                 // wave-uniform dest
            int gi = gi0 + lane;
            int sn = gi >> 4, ss = gi & 15;
            int sl = ss ^ (sn & 15);
            int n  = (sl >> 2) * 32 + sn;
            const unsigned short* gp = wkt + (size_t)(nt * 128 + n) * 512 + kc * 32 + (sl & 3) * 8;
            gload_lds16(gp, db);
        }
    };

    f32x16 acc[4];
#pragma unroll
    for (int nf = 0; nf < 4; ++nf)
#pragma unroll
        for (int e = 0; e < 16; ++e) acc[nf][e] = 0.f;

    float4 ra[4], rb[4];

    // prologue: depth-2, stage FIFO = [B(2), A(4)] -> 6 vm-ops/stage, 12 in flight
    stageB(0, lds);          loadA(0, ra);
    stageB(1, lds + 8192);   loadA(1, rb);

    auto iter = [&](int kc, float4 (&rg)[4]) {
        if (kc < 15) { VMCNT6; } else { VMCNT0; }     // stage kc resident
        // convert A(kc) -> fragments (reg-only, pre-barrier)
        short8 af[2];
        {
            union { short8 s; unsigned u[4]; } u0, u1;
            u0.u[0] = pk2(rg[0].x, rg[0].y); u0.u[1] = pk2(rg[0].z, rg[0].w);
            u0.u[2] = pk2(rg[1].x, rg[1].y); u0.u[3] = pk2(rg[1].z, rg[1].w);
            u1.u[0] = pk2(rg[2].x, rg[2].y); u1.u[1] = pk2(rg[2].z, rg[2].w);
            u1.u[2] = pk2(rg[3].x, rg[3].y); u1.u[3] = pk2(rg[3].z, rg[3].w);
            af[0] = u0.s; af[1] = u1.s;
        }
        __builtin_amdgcn_s_barrier();                 // B(kc) fully resident
        __builtin_amdgcn_sched_barrier(0);
        if (kc < 14) {                                // issue stage kc+2: [B, A]
            stageB(kc + 2, lds + ((kc + 2) % 3) * 8192);
            loadA(kc + 2, rg);
        }
        const char* Bb = lds + (kc % 3) * 8192;
#pragma unroll
        for (int ks = 0; ks < 2; ++ks) {
#pragma unroll
            for (int nf = 0; nf < 4; ++nf) {
                int sl = nf * 4 + ks * 2 + g;
                short8 bf = *(const short8*)(Bb + l31 * 256 + ((sl ^ (l31 & 15)) << 4));
                acc[nf] = __builtin_amdgcn_mfma_f32_32x32x16_bf16(af[ks], bf, acc[nf], 0, 0, 0);
            }
        }
    };

    for (int t2 = 0; t2 < 8; ++t2) {
        iter(t2 * 2,     ra);
        iter(t2 * 2 + 1, rb);
    }

    // ---- epilogue: p[e] = sum_nf Wv[col]*tanh(qb[col]+acc[nf][e]), col = nt*128+nf*32+l31 ----
    float p[16];
#pragma unroll
    for (int nf = 0; nf < 4; ++nf) {
        int col = nt * 128 + nf * 32 + l31;
        float qv  = qb[b * H_ + col];
        float wvv = wv[col];
#pragma unroll
        for (int e = 0; e < 16; ++e) {
            float x  = qv + acc[nf][e];
            float ex = __expf(2.f * x);
            float th = 1.f - 2.f / (ex + 1.f);
            float v  = wvv * th;
            p[e] = nf ? (p[e] + v) : v;
        }
    }

    __syncthreads();                                  // all GEMM LDS reads done before reuse
    // ---- reduce over 32 lanes via LDS transpose: 128 rows x 36 floats (r10-verified) ----
    float* ps = (float*)lds;
#pragma unroll
    for (int e = 0; e < 16; ++e) {
        int row = wave * 32 + (e & 3) + 8 * (e >> 2) + 4 * g;
        ps[row * 36 + l31] = p[e];
    }
    __syncthreads();
    {
        int rr   = tid & 127;
        int half = tid >> 7;
        const float* myrow = ps + rr * 36 + half * 16;
        float rsum = 0.f;
#pragma unroll
        for (int j = 0; j < 4; ++j) {
            float4 v = *(const float4*)(myrow + j * 4);
            rsum += (v.x + v.y) + (v.z + v.w);
        }
        float* pf = (float*)(lds + 18432);            // 256 floats
        pf[half * 128 + rr] = rsum;
        __syncthreads();
        if (tid < 128) {
            float v = pf[tid] + pf[128 + tid];
            int s = s0 + tid;
            part[((size_t)b * S_ + s) * 4 + nt] = v;
        }
    }
}

// ---------------- masked softmax over S per batch row (sums 4 partials) ----------------
__global__ void softmax_kernel(const float* __restrict__ part, const int* __restrict__ mask,
                               const float* __restrict__ bvp, float* __restrict__ attn) {
    __shared__ float red[8];
    int b = blockIdx.x, tid = threadIdx.x;         // 512 threads, 8 waves
    int wid = tid >> 6, lane = tid & 63;
    float bv0 = bvp[0];
    float vals[8];
    float mx = -3.4e38f;
#pragma unroll
    for (int i = 0; i < 8; ++i) {
        int s = i * 512 + tid;
        float4 v = *(const float4*)(part + ((size_t)b * S_ + s) * 4);
        float sc = (v.x + v.y) + (v.z + v.w) + bv0;
        sc = mask[(size_t)b * S_ + s] ? sc : NEG_INF_;
        vals[i] = sc;
        mx = fmaxf(mx, sc);
    }
#pragma unroll
    for (int off = 1; off < 64; off <<= 1) mx = fmaxf(mx, __shfl_xor(mx, off));
    if (lane == 0) red[wid] = mx;
    __syncthreads();
    mx = red[0];
#pragma unroll
    for (int w = 1; w < 8; ++w) mx = fmaxf(mx, red[w]);
    __syncthreads();
    float sum = 0.f;
#pragma unroll
    for (int i = 0; i < 8; ++i) { vals[i] = __expf(vals[i] - mx); sum += vals[i]; }
#pragma unroll
    for (int off = 1; off < 64; off <<= 1) sum += __shfl_xor(sum, off);
    if (lane == 0) red[wid] = sum;
    __syncthreads();
    sum = red[0] + red[1] + red[2] + red[3] + red[4] + red[5] + red[6] + red[7];
    float inv = 1.f / sum;
#pragma unroll
    for (int i = 0; i < 8; ++i) attn[(size_t)b * S_ + i * 512 + tid] = vals[i] * inv;
}

// ---------------- context partial sums: part[c][b][e] ----------------
__global__ void ctx_partial(const float* __restrict__ attn, const float* __restrict__ enc,
                            float* __restrict__ part) {
    __shared__ float a[256];
    int c = blockIdx.x, b = blockIdx.y, t = threadIdx.x;   // 256 threads
    a[t] = attn[(size_t)b * S_ + c * 256 + t];
    __syncthreads();
    const float* ep = enc + (size_t)b * S_ * E_ + (size_t)c * 256 * E_ + t * 2;
    float x = 0.f, y = 0.f;
#pragma unroll 4
    for (int s = 0; s < 256; ++s) {
        float2 v = *(const float2*)(ep + (size_t)s * E_);
        x += a[s] * v.x;
        y += a[s] * v.y;
    }
    float* o = part + ((size_t)c * B_ + b) * E_ + t * 2;
    o[0] = x; o[1] = y;
}

__global__ void ctx_reduce(const float* __restrict__ part, float* __restrict__ ctx) {
    int idx = blockIdx.x * 256 + threadIdx.x;       // 0..32767
    float s = 0.f;
#pragma unroll
    for (int c = 0; c < 16; ++c) s += part[(size_t)c * (B_ * E_) + idx];
    ctx[idx] = s;
}

extern "C" void kernel_launch(void* const* d_in, const int* in_sizes, int n_in,
                              void* d_out, int out_size, void* d_ws, size_t ws_size,
                              hipStream_t stream) {
    const float* hidden = (const float*)d_in[0];
    const float* enc    = (const float*)d_in[1];
    const int*   mask   = (const int*)d_in[2];
    const float* Wq     = (const float*)d_in[3];
    const float* bq     = (const float*)d_in[4];
    const float* Wk     = (const float*)d_in[5];
    const float* bk     = (const float*)d_in[6];
    const float* Wv     = (const float*)d_in[7];
    const float* bv     = (const float*)d_in[8];

    float* out  = (float*)d_out;               // [B*E context][B*S attn]
    char*  ws   = (char*)d_ws;
    float*          qbuf   = (float*)ws;                         // 131072 B
    unsigned short* wkt    = (unsigned short*)(ws + 131072);     // 524288 B
    float*          pscore = (float*)(ws + 655360);              // 4 MB [b][s][4]
    float*          cpart  = (float*)(ws + 655360);              // aliases pscore (after softmax)

    float* ctx  = out;
    float* attn = out + B_ * E_;

    prep_wkt<<<1024, 256, 0, stream>>>(Wk, wkt);
    prep_qb<<<64, 256, 0, stream>>>(hidden, Wq, bq, bk, qbuf);
    scores_kernel<<<8192, 256, 0, stream>>>(enc, wkt, qbuf, Wv, pscore);
    softmax_kernel<<<64, 512, 0, stream>>>(pscore, mask, bv, attn);
    ctx_partial<<<dim3(16, 64), 256, 0, stream>>>(attn, enc, cpart);
    ctx_reduce<<<128, 256, 0, stream>>>(cpart, ctx);
}

// Round 13
// 421.404 us; speedup vs baseline: 2.2867x; 2.2867x over previous
//
#include <hip/hip_runtime.h>
#include <hip/hip_bf16.h>

#define B_ 64
#define S_ 4096
#define H_ 512
#define E_ 512
#define NEG_INF_ -1e10f

typedef __attribute__((ext_vector_type(8))) short short8;
typedef __attribute__((ext_vector_type(16))) float f32x16;

static __device__ __forceinline__ unsigned short f2bf(float f) {
    union { float f; unsigned u; } v; v.f = f;
    unsigned x = v.u;
    x += 0x7FFFu + ((x >> 16) & 1u);   // round-to-nearest-even
    return (unsigned short)(x >> 16);
}

// vendor RNE pair conversion (verified r3/r5-r12: absmax 4.9e-4)
static __device__ __forceinline__ unsigned pk2(float lo, float hi) {
    float2 f; f.x = lo; f.y = hi;
    union { __hip_bfloat162 h; unsigned u; } c;
    c.h = __float22bfloat162_rn(f);
    return c.u;
}

static __device__ __forceinline__ void gload_lds16(const void* g, void* l) {
    __builtin_amdgcn_global_load_lds(
        (const __attribute__((address_space(1))) void*)g,
        (__attribute__((address_space(3))) void*)l, 16, 0, 0);
}

// ---------------- prep: Wkt[h][e] = bf16(Wk[e][h]) ----------------
__global__ void prep_wkt(const float* __restrict__ wk, unsigned short* __restrict__ wkt) {
    int idx = blockIdx.x * 256 + threadIdx.x;
    int h = idx >> 9, e = idx & 511;
    wkt[idx] = f2bf(wk[e * H_ + h]);
}

// ---------------- prep: qb[b][h] = hidden[b]@Wq[:,h] + bq[h] + bk[h] ----------------
__global__ void prep_qb(const float* __restrict__ hidden, const float* __restrict__ wq,
                        const float* __restrict__ bq, const float* __restrict__ bk,
                        float* __restrict__ qb) {
    __shared__ float hid[H_];
    int b = blockIdx.x, t = threadIdx.x;           // 256 threads
    hid[t]       = hidden[b * H_ + t];
    hid[t + 256] = hidden[b * H_ + t + 256];
    __syncthreads();
    for (int hh = t; hh < H_; hh += 256) {
        float s = 0.f;
        for (int e = 0; e < H_; ++e) s += hid[e] * wq[e * H_ + hh];
        qb[b * H_ + hh] = s + bq[hh] + bk[hh];
    }
}

// ---------------- main: partial scores over one 128-col n-chunk ----------------
// m97-faithful COMPILER-SCHEDULED loop (no asm waits / sched_barrier / raw s_barrier —
// m141 evidence: manual order-pinning is what capped r5-r12 at ~350us).
// grid 8192: xcd-chunked -> (b, s-tile 128, n-tile 128). block 256 thr = 4 waves (2M x 2N),
// wave tile 64x64, acc 2x2 of 32x32. BK=64 (8 K-steps, 2 barriers each), single-buffer LDS:
// A[2 panels][32 srows][16 slots]x16B (XOR slot^(srow&15), r6-verified) staged via
// f32 regs + pk2 + ds_write_b128; B same shape via source-permuted global_load_lds (r5+).
__global__ __launch_bounds__(256, 3) void scores_kernel(
    const float* __restrict__ enc, const unsigned short* __restrict__ wkt,
    const float* __restrict__ qb, const float* __restrict__ wv,
    float* __restrict__ part)
{
    __shared__ char lds[38912];   // main: A@0 (16K), B@16K (16K); epilogue: ps@0 (36864), pf@36864

    int id = blockIdx.x;
    int xcd = id & 7, qq = id >> 3;
    int logical = xcd * 1024 + qq;
    int b  = logical >> 7;
    int r  = logical & 127;
    int st = r >> 2, nt = r & 3;
    int s0 = st * 128;

    const int tid  = threadIdx.x;
    const int lane = tid & 63;
    const int wave = tid >> 6;
    const int wr   = wave >> 1;      // M half (0,1)
    const int wc   = wave & 1;       // N half (0,1)
    const int l31  = lane & 31;
    const int g    = lane >> 5;

    const float* encb = enc + ((size_t)b * S_ + s0) * E_;

    // ---- A: thread t handles sids 2t,2t+1; sid -> row=sid>>2 (0..127), ksl=sid&3 (k=ksl*8) ----
    auto loadA = [&](int kc, float4 (&rg)[8]) {
#pragma unroll
        for (int j = 0; j < 2; ++j) {
            int sid = tid * 2 + j;
            int row = sid >> 2, ksl = sid & 3;
            const float* pr = encb + (size_t)row * 512 + kc * 64 + ksl * 8;
#pragma unroll
            for (int kk = 0; kk < 2; ++kk) {
                rg[j * 4 + kk * 2 + 0] = *(const float4*)(pr + kk * 32);
                rg[j * 4 + kk * 2 + 1] = *(const float4*)(pr + kk * 32 + 4);
            }
        }
    };
    auto writeA = [&](const float4 (&rg)[8]) {
#pragma unroll
        for (int j = 0; j < 2; ++j) {
            int sid = tid * 2 + j;
            int row = sid >> 2, ksl = sid & 3;
            int srow = row & 31;
            int sst  = ((row >> 5) * 4 + ksl) ^ (srow & 15);
#pragma unroll
            for (int kk = 0; kk < 2; ++kk) {
                const float4& a = rg[j * 4 + kk * 2 + 0];
                const float4& c = rg[j * 4 + kk * 2 + 1];
                union { short8 s; unsigned u[4]; } u;
                u.u[0] = pk2(a.x, a.y); u.u[1] = pk2(a.z, a.w);
                u.u[2] = pk2(c.x, c.y); u.u[3] = pk2(c.z, c.w);
                *(short8*)(lds + kk * 8192 + srow * 256 + sst * 16) = u.s;
            }
        }
    };
    // ---- B: per kc two 8KB panels [sn 32][16]: sl = ss^(sn&15); n=(sl>>2)*32+sn; k=(sl&3)*8 ----
    auto stageB = [&](int kc) {
#pragma unroll
        for (int kk = 0; kk < 2; ++kk) {
            char* buf = lds + 16384 + kk * 8192;
#pragma unroll
            for (int p = 0; p < 2; ++p) {
                int gi0 = p * 256 + wave * 64;
                char* db = buf + gi0 * 16;             // wave-uniform dest
                int gi = gi0 + lane;
                int sn = gi >> 4, ss = gi & 15;
                int sl = ss ^ (sn & 15);
                int n  = (sl >> 2) * 32 + sn;
                const unsigned short* gp =
                    wkt + (size_t)(nt * 128 + n) * 512 + kc * 64 + kk * 32 + (sl & 3) * 8;
                gload_lds16(gp, db);
            }
        }
    };

    f32x16 acc[2][2];
#pragma unroll
    for (int mr = 0; mr < 2; ++mr)
#pragma unroll
        for (int nf = 0; nf < 2; ++nf)
#pragma unroll
            for (int e = 0; e < 16; ++e) acc[mr][nf][e] = 0.f;

    float4 ar[8];
    loadA(0, ar);

    for (int kc = 0; kc < 8; ++kc) {
        __syncthreads();                  // previous compute done; LDS reusable
        writeA(ar);                       // pk2 + ds_write (compiler inserts waits)
        stageB(kc);                       // 4x global_load_lds dwordx4
        __syncthreads();                  // staged tile resident
        if (kc < 7) loadA(kc + 1, ar);    // next A f32 loads overlap compute
        const char* Ap = lds;
        const char* Bp = lds + 16384;
#pragma unroll
        for (int kst = 0; kst < 4; ++kst) {
            const int kk = kst >> 1, ks = kst & 1;
            short8 af[2], bf[2];
#pragma unroll
            for (int mr = 0; mr < 2; ++mr) {
                int sl = (wr * 2 + mr) * 4 + ks * 2 + g;
                af[mr] = *(const short8*)(Ap + kk * 8192 + l31 * 256 + ((sl ^ (l31 & 15)) << 4));
            }
#pragma unroll
            for (int nf = 0; nf < 2; ++nf) {
                int sl = (wc * 2 + nf) * 4 + ks * 2 + g;
                bf[nf] = *(const short8*)(Bp + kk * 8192 + l31 * 256 + ((sl ^ (l31 & 15)) << 4));
            }
            acc[0][0] = __builtin_amdgcn_mfma_f32_32x32x16_bf16(af[0], bf[0], acc[0][0], 0, 0, 0);
            acc[0][1] = __builtin_amdgcn_mfma_f32_32x32x16_bf16(af[0], bf[1], acc[0][1], 0, 0, 0);
            acc[1][0] = __builtin_amdgcn_mfma_f32_32x32x16_bf16(af[1], bf[0], acc[1][0], 0, 0, 0);
            acc[1][1] = __builtin_amdgcn_mfma_f32_32x32x16_bf16(af[1], bf[1], acc[1][1], 0, 0, 0);
        }
    }

    // ---- epilogue: p = sum_nf Wv[col]*tanh(qb[col]+acc)  (r6-verified) ----
    float p[2][16];
#pragma unroll
    for (int nf = 0; nf < 2; ++nf) {
        int col = nt * 128 + wc * 64 + nf * 32 + l31;
        float qv  = qb[b * H_ + col];
        float wvv = wv[col];
#pragma unroll
        for (int mr = 0; mr < 2; ++mr)
#pragma unroll
            for (int e = 0; e < 16; ++e) {
                float x  = qv + acc[mr][nf][e];
                float ex = __expf(2.f * x);
                float th = 1.f - 2.f / (ex + 1.f);
                float v  = wvv * th;
                p[mr][e] = nf ? (p[mr][e] + v) : v;
            }
    }

    __syncthreads();                                  // all GEMM LDS traffic done before reuse
    // ---- reduce over 32 lanes via LDS transpose (stride 36 floats; r3/r6-verified) ----
    float* ps = (float*)lds;                          // [wave][64 rows][36]
#pragma unroll
    for (int mr = 0; mr < 2; ++mr)
#pragma unroll
        for (int e = 0; e < 16; ++e) {
            int row = mr * 32 + (e & 3) + 8 * (e >> 2) + 4 * g;
            ps[(wave * 64 + row) * 36 + l31] = p[mr][e];
        }
    __syncthreads();
    float rsum = 0.f;
    {
        const float* myrow = ps + (size_t)(wave * 64 + lane) * 36;
#pragma unroll
        for (int j = 0; j < 8; ++j) {
            float4 v = *(const float4*)(myrow + j * 4);
            rsum += (v.x + v.y) + (v.z + v.w);
        }
    }
    float* pf = (float*)(lds + 36864);                // 256 floats
    pf[wave * 64 + lane] = rsum;
    __syncthreads();
    if (tid < 128) {
        int wr2 = tid >> 6, rr = tid & 63;
        float v = pf[(wr2 * 2 + 0) * 64 + rr] + pf[(wr2 * 2 + 1) * 64 + rr];
        int s = s0 + wr2 * 64 + rr;
        part[((size_t)b * S_ + s) * 4 + nt] = v;
    }
}

// ---------------- masked softmax over S per batch row (sums 4 partials) ----------------
__global__ void softmax_kernel(const float* __restrict__ part, const int* __restrict__ mask,
                               const float* __restrict__ bvp, float* __restrict__ attn) {
    __shared__ float red[8];
    int b = blockIdx.x, tid = threadIdx.x;         // 512 threads, 8 waves
    int wid = tid >> 6, lane = tid & 63;
    float bv0 = bvp[0];
    float vals[8];
    float mx = -3.4e38f;
#pragma unroll
    for (int i = 0; i < 8; ++i) {
        int s = i * 512 + tid;
        float4 v = *(const float4*)(part + ((size_t)b * S_ + s) * 4);
        float sc = (v.x + v.y) + (v.z + v.w) + bv0;
        sc = mask[(size_t)b * S_ + s] ? sc : NEG_INF_;
        vals[i] = sc;
        mx = fmaxf(mx, sc);
    }
#pragma unroll
    for (int off = 1; off < 64; off <<= 1) mx = fmaxf(mx, __shfl_xor(mx, off));
    if (lane == 0) red[wid] = mx;
    __syncthreads();
    mx = red[0];
#pragma unroll
    for (int w = 1; w < 8; ++w) mx = fmaxf(mx, red[w]);
    __syncthreads();
    float sum = 0.f;
#pragma unroll
    for (int i = 0; i < 8; ++i) { vals[i] = __expf(vals[i] - mx); sum += vals[i]; }
#pragma unroll
    for (int off = 1; off < 64; off <<= 1) sum += __shfl_xor(sum, off);
    if (lane == 0) red[wid] = sum;
    __syncthreads();
    sum = red[0] + red[1] + red[2] + red[3] + red[4] + red[5] + red[6] + red[7];
    float inv = 1.f / sum;
#pragma unroll
    for (int i = 0; i < 8; ++i) attn[(size_t)b * S_ + i * 512 + tid] = vals[i] * inv;
}

// ---------------- context partial sums: part[c][b][e] ----------------
__global__ void ctx_partial(const float* __restrict__ attn, const float* __restrict__ enc,
                            float* __restrict__ part) {
    __shared__ float a[256];
    int c = blockIdx.x, b = blockIdx.y, t = threadIdx.x;   // 256 threads
    a[t] = attn[(size_t)b * S_ + c * 256 + t];
    __syncthreads();
    const float* ep = enc + (size_t)b * S_ * E_ + (size_t)c * 256 * E_ + t * 2;
    float x = 0.f, y = 0.f;
#pragma unroll 4
    for (int s = 0; s < 256; ++s) {
        float2 v = *(const float2*)(ep + (size_t)s * E_);
        x += a[s] * v.x;
        y += a[s] * v.y;
    }
    float* o = part + ((size_t)c * B_ + b) * E_ + t * 2;
    o[0] = x; o[1] = y;
}

__global__ void ctx_reduce(const float* __restrict__ part, float* __restrict__ ctx) {
    int idx = blockIdx.x * 256 + threadIdx.x;       // 0..32767
    float s = 0.f;
#pragma unroll
    for (int c = 0; c < 16; ++c) s += part[(size_t)c * (B_ * E_) + idx];
    ctx[idx] = s;
}

extern "C" void kernel_launch(void* const* d_in, const int* in_sizes, int n_in,
                              void* d_out, int out_size, void* d_ws, size_t ws_size,
                              hipStream_t stream) {
    const float* hidden = (const float*)d_in[0];
    const float* enc    = (const float*)d_in[1];
    const int*   mask   = (const int*)d_in[2];
    const float* Wq     = (const float*)d_in[3];
    const float* bq     = (const float*)d_in[4];
    const float* Wk     = (const float*)d_in[5];
    const float* bk     = (const float*)d_in[6];
    const float* Wv     = (const float*)d_in[7];
    const float* bv     = (const float*)d_in[8];

    float* out  = (float*)d_out;               // [B*E context][B*S attn]
    char*  ws   = (char*)d_ws;
    float*          qbuf   = (float*)ws;                         // 131072 B
    unsigned short* wkt    = (unsigned short*)(ws + 131072);     // 524288 B
    float*          pscore = (float*)(ws + 655360);              // 4 MB [b][s][4]
    float*          cpart  = (float*)(ws + 655360);              // aliases pscore (after softmax)

    float* ctx  = out;
    float* attn = out + B_ * E_;

    prep_wkt<<<1024, 256, 0, stream>>>(Wk, wkt);
    prep_qb<<<64, 256, 0, stream>>>(hidden, Wq, bq, bk, qbuf);
    scores_kernel<<<8192, 256, 0, stream>>>(enc, wkt, qbuf, Wv, pscore);
    softmax_kernel<<<64, 512, 0, stream>>>(pscore, mask, bv, attn);
    ctx_partial<<<dim3(16, 64), 256, 0, stream>>>(attn, enc, cpart);
    ctx_reduce<<<128, 256, 0, stream>>>(cpart, ctx);
}